// Round 9
// baseline (535.056 us; speedup 1.0000x reference)
//
#include <hip/hip_runtime.h>
#include <math.h>

#define NN 50000
#define NE 1600000
#define DF 256
#define NBUCK 391   // ceil(NN/128); bucket = dst >> 7
#define CHS4 ((long long)NN * 64)   // ushorts per 64-dim feature chunk (6.4MB)
#define HALFN 25000
#define PASSES 7
#define AGSETS 256
#define AGG_BLOCKS (AGSETS * 4)     // 1024 = 4 blocks/CU, all co-resident

typedef unsigned short ushortT;
typedef __attribute__((ext_vector_type(8))) short short8;
typedef __attribute__((ext_vector_type(4))) float floatx4;
typedef __attribute__((ext_vector_type(4))) unsigned uintx4;

__device__ __forceinline__ unsigned bf16rne(float f) {
    unsigned u = __float_as_uint(f);
    return (u + 0x7fffu + ((u >> 16) & 1u)) >> 16;
}

#define ASYNC16(gptr, ldsptr) \
    __builtin_amdgcn_global_load_lds((const __attribute__((address_space(1))) unsigned*)(gptr), \
                                     (__attribute__((address_space(3))) unsigned*)(ldsptr), 16, 0, 0)

// ---------------- CSR build via bucket binning ----------------

__global__ void k_zero(int* __restrict__ bcnt) {
    int i = blockIdx.x * 256 + threadIdx.x;
    if (i < NBUCK) bcnt[i] = 0;
}

__global__ __launch_bounds__(256)
void k_bhist(const int* __restrict__ dst, int* __restrict__ bcnt) {
    __shared__ int h[NBUCK];
    for (int i = threadIdx.x; i < NBUCK; i += 256) h[i] = 0;
    __syncthreads();
    int base = blockIdx.x * 4096;
#pragma unroll
    for (int i = 0; i < 16; ++i) {
        int e = base + i * 256 + threadIdx.x;
        if (e < NE) atomicAdd(&h[dst[e] >> 7], 1);
    }
    __syncthreads();
    for (int i = threadIdx.x; i < NBUCK; i += 256)
        if (h[i]) atomicAdd(&bcnt[i], h[i]);
}

__global__ void k_bscan(const int* __restrict__ bcnt, int* __restrict__ bbase,
                        int* __restrict__ cursor, int* __restrict__ row_ptr,
                        float* __restrict__ nrm) {
    __shared__ int s[512];
    int t = threadIdx.x;
    int v = (t < NBUCK) ? bcnt[t] : 0;
    s[t] = v; __syncthreads();
    for (int off = 1; off < 512; off <<= 1) {
        int x = (t >= off) ? s[t - off] : 0;
        __syncthreads();
        s[t] += x;
        __syncthreads();
    }
    if (t < NBUCK) { bbase[t] = s[t] - v; cursor[t] = s[t] - v; }
    if (t == 0) { bbase[NBUCK] = NE; row_ptr[NN] = NE; *nrm = 0.0f; }
}

__global__ __launch_bounds__(256)
void k_bin(const int* __restrict__ src, const int* __restrict__ dst,
           int* __restrict__ cursor, unsigned* __restrict__ rec) {
    __shared__ int h[NBUCK];
    __shared__ int gb[NBUCK];
    for (int i = threadIdx.x; i < NBUCK; i += 256) h[i] = 0;
    __syncthreads();
    const int base = blockIdx.x * 2048;
    int bk[8], rk[8];
    unsigned pk[8];
#pragma unroll
    for (int i = 0; i < 8; ++i) {
        int e = base + i * 256 + threadIdx.x;
        if (e < NE) {
            int d = dst[e];
            bk[i] = d >> 7;
            pk[i] = (unsigned)src[e] | ((unsigned)(d & 127) << 16);
            rk[i] = atomicAdd(&h[bk[i]], 1);
        } else bk[i] = -1;
    }
    __syncthreads();
    for (int i = threadIdx.x; i < NBUCK; i += 256) {
        int c = h[i];
        gb[i] = c ? atomicAdd(&cursor[i], c) : 0;
    }
    __syncthreads();
#pragma unroll
    for (int i = 0; i < 8; ++i)
        if (bk[i] >= 0) rec[gb[bk[i]] + rk[i]] = pk[i];
}

// k_csr: per node, edges ordered [src<HALFN][src>=HALFN]; hp[n] = boundary.
// row_ptr/hp computed from the immutable scan (s[], cnt[]), not mutable cur[].

__global__ __launch_bounds__(256)
void k_csr(const unsigned* __restrict__ rec, const int* __restrict__ bbase,
           int* __restrict__ row_ptr, int* __restrict__ hp, ushortT* __restrict__ csr) {
    __shared__ int cnt[256];
    __shared__ int cur[256];
    __shared__ int s[256];
    const int B = blockIdx.x, t = threadIdx.x;
    cnt[t] = 0;
    __syncthreads();
    const int beg = bbase[B], end = bbase[B + 1];
    for (int p = beg + t; p < end; p += 256) {
        unsigned r = rec[p];
        int idx = (int)((r >> 16) & 127) * 2 + ((r & 0xffffu) >= HALFN ? 1 : 0);
        atomicAdd(&cnt[idx], 1);
    }
    __syncthreads();
    int v = cnt[t];
    s[t] = v; __syncthreads();
    for (int off = 1; off < 256; off <<= 1) {
        int x = (t >= off) ? s[t - off] : 0;
        __syncthreads();
        s[t] += x;
        __syncthreads();
    }
    cur[t] = s[t] - v;
    __syncthreads();
    if (t < 128) {
        int node = B * 128 + t;
        if (node < NN) {
            row_ptr[node] = beg + s[2 * t] - cnt[2 * t];
            hp[node]      = beg + s[2 * t + 1] - cnt[2 * t + 1];
        }
    }
    for (int p = beg + t; p < end; p += 256) {
        unsigned r = rec[p];
        int idx = (int)((r >> 16) & 127) * 2 + ((r & 0xffffu) >= HALFN ? 1 : 0);
        int loc = atomicAdd(&cur[idx], 1);
        csr[beg + loc] = (ushortT)r;
    }
}

// ---------------- conversions (merged) ----------------
// blocks [0,6250): emb gather+cvt -> CHUNKED bf16 layout [4][NN][64]
// [6250,6762): Wt0; [6762,7274): Wt1

__global__ __launch_bounds__(256)
void k_cvt(const float* __restrict__ emb, const int* __restrict__ gather,
           ushortT* __restrict__ embb,
           const float* __restrict__ Ws0, const float* __restrict__ Wn0,
           ushortT* __restrict__ Wt0,
           const float* __restrict__ Ws1, const float* __restrict__ Wn1,
           ushortT* __restrict__ Wt1) {
    const int b = blockIdx.x;
    if (b < 6250) {
        long long i = ((long long)b * 256 + threadIdx.x) * 8;
        int row = (int)(i >> 8);
        int col = (int)(i & 255);
        long long g = (long long)gather[row] * 256 + col;
        float4 v0 = *(const float4*)(emb + g);
        float4 v1 = *(const float4*)(emb + g + 4);
        uint4 o;
        o.x = bf16rne(v0.x) | (bf16rne(v0.y) << 16);
        o.y = bf16rne(v0.z) | (bf16rne(v0.w) << 16);
        o.z = bf16rne(v1.x) | (bf16rne(v1.y) << 16);
        o.w = bf16rne(v1.z) | (bf16rne(v1.w) << 16);
        // chunked4: [col>>6][row][col&63]
        *(uint4*)(embb + ((long long)(col >> 6) * NN + row) * 64 + (col & 63)) = o;
    } else {
        const bool first = b < 6762;
        const int idx = ((first ? b - 6250 : b - 6762)) * 256 + threadIdx.x;
        const int n = idx >> 9;
        const int k = idx & 511;
        const float* Ws = first ? Ws0 : Ws1;
        const float* Wn = first ? Wn0 : Wn1;
        float v = (k < 256) ? Ws[k * 256 + n] : Wn[(k - 256) * 256 + n];
        (first ? Wt0 : Wt1)[idx] = (ushortT)bf16rne(v);
    }
}

// ---------------- neighbor mean aggregation: persistent phase-aligned ----------
// feat [4 chunks][NN][64] bf16, 128B rows. chunk = blockIdx&3 -> XCD pair.
// 1024 blocks, ALL co-resident (4/CU at <=128 VGPR). Each block owns up to 7
// node-groups; GLOBAL phase 0 first: every block processes all its nodes'
// src<HALFN edges (rows 0..24999 of the chunk = 3.2MB, L2-resident), partials
// held in REGISTERS (7x8 floats); then global phase 1 (src>=HALFN, the other
// 3.2MB) and store. Descriptors loaded once. No partial-sum memory traffic.

#define ACCUM8(S, q) do { \
        S[0] += __uint_as_float(q.x << 16); \
        S[1] += __uint_as_float(q.x & 0xffff0000u); \
        S[2] += __uint_as_float(q.y << 16); \
        S[3] += __uint_as_float(q.y & 0xffff0000u); \
        S[4] += __uint_as_float(q.z << 16); \
        S[5] += __uint_as_float(q.z & 0xffff0000u); \
        S[6] += __uint_as_float(q.w << 16); \
        S[7] += __uint_as_float(q.w & 0xffff0000u); \
    } while (0)

#define ACC_RANGE(LO, HI, S) do { \
        int p_ = (LO); const int hi_ = (HI); \
        if (p_ < hi_ && (p_ & 1)) { \
            int i0_ = (int)__builtin_nontemporal_load(csr + p_); \
            uintx4 q_ = *(const uintx4*)(fc + i0_ * 64 + part); \
            ACCUM8(S, q_); ++p_; \
        } \
        unsigned x0_ = 0, x1_ = 0, x2_ = 0, x3_ = 0; \
        if (p_ + 7 < hi_) { \
            const unsigned* cp_ = (const unsigned*)(csr + p_); \
            x0_ = __builtin_nontemporal_load(cp_ + 0); \
            x1_ = __builtin_nontemporal_load(cp_ + 1); \
            x2_ = __builtin_nontemporal_load(cp_ + 2); \
            x3_ = __builtin_nontemporal_load(cp_ + 3); \
        } \
        while (p_ + 7 < hi_) { \
            uintx4 q0_ = *(const uintx4*)(fc + (int)(x0_ & 0xffffu) * 64 + part); \
            uintx4 q1_ = *(const uintx4*)(fc + (int)(x0_ >> 16)     * 64 + part); \
            uintx4 q2_ = *(const uintx4*)(fc + (int)(x1_ & 0xffffu) * 64 + part); \
            uintx4 q3_ = *(const uintx4*)(fc + (int)(x1_ >> 16)     * 64 + part); \
            uintx4 q4_ = *(const uintx4*)(fc + (int)(x2_ & 0xffffu) * 64 + part); \
            uintx4 q5_ = *(const uintx4*)(fc + (int)(x2_ >> 16)     * 64 + part); \
            uintx4 q6_ = *(const uintx4*)(fc + (int)(x3_ & 0xffffu) * 64 + part); \
            uintx4 q7_ = *(const uintx4*)(fc + (int)(x3_ >> 16)     * 64 + part); \
            const int np_ = p_ + 8; \
            if (np_ + 7 < hi_) { \
                const unsigned* cp_ = (const unsigned*)(csr + np_); \
                x0_ = __builtin_nontemporal_load(cp_ + 0); \
                x1_ = __builtin_nontemporal_load(cp_ + 1); \
                x2_ = __builtin_nontemporal_load(cp_ + 2); \
                x3_ = __builtin_nontemporal_load(cp_ + 3); \
            } \
            ACCUM8(S, q0_); ACCUM8(S, q1_); ACCUM8(S, q2_); ACCUM8(S, q3_); \
            ACCUM8(S, q4_); ACCUM8(S, q5_); ACCUM8(S, q6_); ACCUM8(S, q7_); \
            p_ = np_; \
        } \
        for (; p_ < hi_; ++p_) { \
            int i0_ = (int)__builtin_nontemporal_load(csr + p_); \
            uintx4 q_ = *(const uintx4*)(fc + i0_ * 64 + part); \
            ACCUM8(S, q_); \
        } \
    } while (0)

__global__ __launch_bounds__(256, 4)
void k_agg(const ushortT* __restrict__ feat, const int* __restrict__ row_ptr,
           const int* __restrict__ hp, const ushortT* __restrict__ csr,
           ushortT* __restrict__ out) {
    const int c    = blockIdx.x & 3;
    const int gset = blockIdx.x >> 2;          // 0..255
    const int oct  = threadIdx.x >> 3;         // 0..31 (octet = one node)
    const int part = (threadIdx.x & 7) * 8;    // ushort offset within 64-elem row
    const ushortT* fc = feat + (long long)c * CHS4;

    int rbegv[PASSES], hbv[PASSES], rendv[PASSES];
    float s[PASSES][8];

    // load all descriptors up front (one latency for all passes)
#pragma unroll
    for (int ps = 0; ps < PASSES; ++ps) {
        const int node = (ps * AGSETS + gset) * 32 + oct;
        if (node < NN) {
            rbegv[ps] = row_ptr[node];
            rendv[ps] = row_ptr[node + 1];
            hbv[ps]   = hp[node];
        } else { rbegv[ps] = 0; hbv[ps] = 0; rendv[ps] = 0; }
#pragma unroll
        for (int k = 0; k < 8; ++k) s[ps][k] = 0.f;
    }

    // ---- global phase 0: src rows [0, HALFN) -- 3.2MB/chunk, L2-resident ----
#pragma unroll
    for (int ps = 0; ps < PASSES; ++ps)
        ACC_RANGE(rbegv[ps], hbv[ps], s[ps]);

    // ---- global phase 1: src rows [HALFN, NN) -- the other 3.2MB ----
#pragma unroll
    for (int ps = 0; ps < PASSES; ++ps) {
        ACC_RANGE(hbv[ps], rendv[ps], s[ps]);
        const int node = (ps * AGSETS + gset) * 32 + oct;
        if (node < NN) {
            const float inv = 1.0f / fmaxf((float)(rendv[ps] - rbegv[ps]), 1.0f);
            uintx4 o;
            o.x = bf16rne(s[ps][0] * inv) | (bf16rne(s[ps][1] * inv) << 16);
            o.y = bf16rne(s[ps][2] * inv) | (bf16rne(s[ps][3] * inv) << 16);
            o.z = bf16rne(s[ps][4] * inv) | (bf16rne(s[ps][5] * inv) << 16);
            o.w = bf16rne(s[ps][6] * inv) | (bf16rne(s[ps][7] * inv) << 16);
            __builtin_nontemporal_store(o, (uintx4*)(out + ((long long)c * NN + node) * 64 + part));
        }
    }
}

// ---------------- dual GEMM, 128x256 tile, 512 threads (8 waves, 2M x 4N) -----
// A is chunked [4][NN][64]: k-tile 32 = half a chunk row. K=512 concat:
// kt<256 self, else neigh. Layer-0 C-write goes back to chunked4 layout.

template<int RELU, int NORM>
__global__ __launch_bounds__(512, 2)
void k_gemm(const ushortT* __restrict__ Aself, const ushortT* __restrict__ Aneigh,
            const ushortT* __restrict__ Wt, const float* __restrict__ bias,
            ushortT* __restrict__ Cb, float* __restrict__ Cf, float* __restrict__ norm_acc) {
    __shared__ ushortT As[4096];   // [128 m][32 k]
    __shared__ ushortT Bs[8192];   // [256 n][32 k]
    __shared__ float red[8];

    const int t = threadIdx.x;
    const int w = t >> 6;          // wave 0..7
    const int lane = t & 63;
    const int wm = w >> 2;         // 0..1  (M half)
    const int wn = w & 3;          // 0..3  (N quarter)
    const int m0 = blockIdx.x * 128;

    const int ar = t >> 2;        // staging row (0..127)
    const int cu = (t & 3) * 8;   // ushort offset within 32-elem k-row

    const long long gA = (long long)min(m0 + ar, NN - 1) * 64 + cu;

    const unsigned ldsA = w * 512;   // wave-uniform base (ushorts); +lane*16B by HW
    const unsigned ldsB = w * 512;

    const int fm = lane & 15;
    const int fk = (lane >> 4) * 8;

    floatx4 acc[4][4];
#pragma unroll
    for (int i = 0; i < 4; ++i)
#pragma unroll
        for (int j = 0; j < 4; ++j) acc[i][j] = (floatx4){0.f, 0.f, 0.f, 0.f};

    for (int kt = 0; kt < 512; kt += 32) {
        const int kc = (kt < 256) ? kt : kt - 256;
        const ushortT* Ab = ((kt < 256) ? Aself : Aneigh)
                          + (long long)(kc >> 6) * CHS4 + (kc & 32);

        __syncthreads();
        ASYNC16(Ab + gA, As + ldsA);
#pragma unroll
        for (int i = 0; i < 2; ++i)
            ASYNC16(Wt + (i * 128 + ar) * 512 + kt + cu, Bs + i * 4096 + ldsB);
        __syncthreads();

        short8 af[4], bf[4];
#pragma unroll
        for (int i = 0; i < 4; ++i)
            af[i] = *(const short8*)&As[(wm * 64 + i * 16 + fm) * 32 + fk];
#pragma unroll
        for (int j = 0; j < 4; ++j)
            bf[j] = *(const short8*)&Bs[(wn * 64 + j * 16 + fm) * 32 + fk];
#pragma unroll
        for (int i = 0; i < 4; ++i)
#pragma unroll
            for (int j = 0; j < 4; ++j)
                acc[i][j] = __builtin_amdgcn_mfma_f32_16x16x32_bf16(af[i], bf[j], acc[i][j], 0, 0, 0);
    }

    float bj[4];
#pragma unroll
    for (int j = 0; j < 4; ++j) bj[j] = bias[wn * 64 + j * 16 + fm];

    float sumsq = 0.0f;
#pragma unroll
    for (int i = 0; i < 4; ++i) {
#pragma unroll
        for (int r = 0; r < 4; ++r) {
            const int row = m0 + wm * 64 + i * 16 + (lane >> 4) * 4 + r;
            if (row < NN) {
#pragma unroll
                for (int j = 0; j < 4; ++j) {
                    const int col = wn * 64 + j * 16 + fm;
                    float v = acc[i][j][r] + bj[j];
                    if (RELU) v = fmaxf(v, 0.0f);
                    if (NORM) {
                        Cf[(long long)row * 256 + col] = v;
                        sumsq += v * v;
                    } else {
                        Cb[((long long)(col >> 6) * NN + row) * 64 + (col & 63)] = (ushortT)bf16rne(v);
                    }
                }
            }
        }
    }

    if (NORM) {
#pragma unroll
        for (int off = 32; off > 0; off >>= 1) sumsq += __shfl_down(sumsq, off);
        if (lane == 0) red[w] = sumsq;
        __syncthreads();
        if (t == 0) {
            float tot = 0.f;
#pragma unroll
            for (int i = 0; i < 8; ++i) tot += red[i];
            atomicAdd(norm_acc, tot);
        }
    }
}

__global__ void k_scale(float* __restrict__ out, const float* __restrict__ nrm) {
    const float s = 1.0f / sqrtf(*nrm);
    long long i = ((long long)blockIdx.x * 256 + threadIdx.x) * 4;
    float4 v = *(float4*)&out[i];
    v.x *= s; v.y *= s; v.z *= s; v.w *= s;
    *(float4*)&out[i] = v;
}

// ---------------- launch ----------------

extern "C" void kernel_launch(void* const* d_in, const int* in_sizes, int n_in,
                              void* d_out, int out_size, void* d_ws, size_t ws_size,
                              hipStream_t stream) {
    const int*   input_nodes = (const int*)d_in[0];
    const int*   esrc = (const int*)d_in[1];
    const int*   edst = (const int*)d_in[2];
    const float* emb  = (const float*)d_in[3];
    const float* Ws0  = (const float*)d_in[4];
    const float* Wn0  = (const float*)d_in[5];
    const float* b0   = (const float*)d_in[6];
    const float* Ws1  = (const float*)d_in[7];
    const float* Wn1  = (const float*)d_in[8];
    const float* b1   = (const float*)d_in[9];
    float* out = (float*)d_out;

    char* base = (char*)d_ws;
    ushortT*  embb    = (ushortT*) (base);                  // 25,600,000
    ushortT*  h1b     = (ushortT*) (base + 25600000);       // 25,600,000
    ushortT*  hnb     = (ushortT*) (base + 51200000);       // 25,600,000
    unsigned* rec     = (unsigned*)(base + 76800000);       //  6,400,000
    ushortT*  csr     = (ushortT*) (base + 83200000);       //  3,200,000
    ushortT*  Wt0     = (ushortT*) (base + 86400000);       //    262,144
    ushortT*  Wt1     = (ushortT*) (base + 86662144);       //    262,144
    int*      row_ptr = (int*)     (base + 86924288);       //    200,016
    int*      hp      = (int*)     (base + 87124304);       //    200,000
    int*      bcnt    = (int*)     (base + 87324304);       //      1,600
    int*      bbase   = (int*)     (base + 87325904);       //      1,600
    int*      cursor  = (int*)     (base + 87327504);       //      1,600
    float*    nrm     = (float*)   (base + 87329104);       //          4

    k_zero  <<<2,     256, 0, stream>>>(bcnt);
    k_bhist <<<391,   256, 0, stream>>>(edst, bcnt);
    k_bscan <<<1,     512, 0, stream>>>(bcnt, bbase, cursor, row_ptr, nrm);
    k_bin   <<<782,   256, 0, stream>>>(esrc, edst, cursor, rec);
    k_csr   <<<NBUCK, 256, 0, stream>>>(rec, bbase, row_ptr, hp, csr);

    k_cvt<<<7274, 256, 0, stream>>>(emb, input_nodes, embb, Ws0, Wn0, Wt0, Ws1, Wn1, Wt1);

    const int GEMM_BLOCKS = (NN + 127) / 128;     // 391

    // layer 0
    k_agg<<<AGG_BLOCKS, 256, 0, stream>>>(embb, row_ptr, hp, csr, hnb);
    k_gemm<1, 0><<<GEMM_BLOCKS, 512, 0, stream>>>(embb, hnb, Wt0, b0, h1b, nullptr, nullptr);

    // layer 1
    k_agg<<<AGG_BLOCKS, 256, 0, stream>>>(h1b, row_ptr, hp, csr, hnb);
    k_gemm<0, 1><<<GEMM_BLOCKS, 512, 0, stream>>>(h1b, hnb, Wt1, b1, nullptr, out, nrm);

    k_scale<<<NN * DF / 4 / 256, 256, 0, stream>>>(out, nrm);
}

// Round 10
// 437.015 us; speedup vs baseline: 1.2243x; 1.2243x over previous
//
#include <hip/hip_runtime.h>
#include <math.h>

#define NN 50000
#define NE 1600000
#define DF 256
#define NBUCK 391   // ceil(NN/128); bucket = dst >> 7
#define CHS4 ((long long)NN * 64)   // ushorts per 64-dim feature chunk (6.4MB)
#define HALFN 25000

typedef unsigned short ushortT;
typedef __attribute__((ext_vector_type(8))) short short8;
typedef __attribute__((ext_vector_type(4))) float floatx4;
typedef __attribute__((ext_vector_type(4))) unsigned uintx4;

__device__ __forceinline__ unsigned bf16rne(float f) {
    unsigned u = __float_as_uint(f);
    return (u + 0x7fffu + ((u >> 16) & 1u)) >> 16;
}

#define ASYNC16(gptr, ldsptr) \
    __builtin_amdgcn_global_load_lds((const __attribute__((address_space(1))) unsigned*)(gptr), \
                                     (__attribute__((address_space(3))) unsigned*)(ldsptr), 16, 0, 0)

// ---------------- CSR build via bucket binning ----------------

__global__ __launch_bounds__(256)
void k_bhist(const int* __restrict__ dst, int* __restrict__ bcnt) {
    __shared__ int h[NBUCK];
    for (int i = threadIdx.x; i < NBUCK; i += 256) h[i] = 0;
    __syncthreads();
    int base = blockIdx.x * 4096;
#pragma unroll
    for (int i = 0; i < 16; ++i) {
        int e = base + i * 256 + threadIdx.x;
        if (e < NE) atomicAdd(&h[dst[e] >> 7], 1);
    }
    __syncthreads();
    for (int i = threadIdx.x; i < NBUCK; i += 256)
        if (h[i]) atomicAdd(&bcnt[i], h[i]);
}

__global__ void k_bscan(const int* __restrict__ bcnt, int* __restrict__ bbase,
                        int* __restrict__ cursor, int* __restrict__ row_ptr,
                        float* __restrict__ nrm) {
    __shared__ int s[512];
    int t = threadIdx.x;
    int v = (t < NBUCK) ? bcnt[t] : 0;
    s[t] = v; __syncthreads();
    for (int off = 1; off < 512; off <<= 1) {
        int x = (t >= off) ? s[t - off] : 0;
        __syncthreads();
        s[t] += x;
        __syncthreads();
    }
    if (t < NBUCK) { bbase[t] = s[t] - v; cursor[t] = s[t] - v; }
    if (t == 0) { bbase[NBUCK] = NE; row_ptr[NN] = NE; *nrm = 0.0f; }
}

__global__ __launch_bounds__(256)
void k_bin(const int* __restrict__ src, const int* __restrict__ dst,
           int* __restrict__ cursor, unsigned* __restrict__ rec) {
    __shared__ int h[NBUCK];
    __shared__ int gb[NBUCK];
    for (int i = threadIdx.x; i < NBUCK; i += 256) h[i] = 0;
    __syncthreads();
    const int base = blockIdx.x * 2048;
    int bk[8], rk[8];
    unsigned pk[8];
#pragma unroll
    for (int i = 0; i < 8; ++i) {
        int e = base + i * 256 + threadIdx.x;
        if (e < NE) {
            int d = dst[e];
            bk[i] = d >> 7;
            pk[i] = (unsigned)src[e] | ((unsigned)(d & 127) << 16);
            rk[i] = atomicAdd(&h[bk[i]], 1);
        } else bk[i] = -1;
    }
    __syncthreads();
    for (int i = threadIdx.x; i < NBUCK; i += 256) {
        int c = h[i];
        gb[i] = c ? atomicAdd(&cursor[i], c) : 0;
    }
    __syncthreads();
#pragma unroll
    for (int i = 0; i < 8; ++i)
        if (bk[i] >= 0) rec[gb[bk[i]] + rk[i]] = pk[i];
}

// k_csr: per node, edges ordered [src<HALFN][src>=HALFN]; hp[n] = boundary.
// row_ptr/hp computed from the immutable scan (s[], cnt[]), not mutable cur[].

__global__ __launch_bounds__(256)
void k_csr(const unsigned* __restrict__ rec, const int* __restrict__ bbase,
           int* __restrict__ row_ptr, int* __restrict__ hp, ushortT* __restrict__ csr) {
    __shared__ int cnt[256];
    __shared__ int cur[256];
    __shared__ int s[256];
    const int B = blockIdx.x, t = threadIdx.x;
    cnt[t] = 0;
    __syncthreads();
    const int beg = bbase[B], end = bbase[B + 1];
    for (int p = beg + t; p < end; p += 256) {
        unsigned r = rec[p];
        int idx = (int)((r >> 16) & 127) * 2 + ((r & 0xffffu) >= HALFN ? 1 : 0);
        atomicAdd(&cnt[idx], 1);
    }
    __syncthreads();
    int v = cnt[t];
    s[t] = v; __syncthreads();
    for (int off = 1; off < 256; off <<= 1) {
        int x = (t >= off) ? s[t - off] : 0;
        __syncthreads();
        s[t] += x;
        __syncthreads();
    }
    cur[t] = s[t] - v;
    __syncthreads();
    if (t < 128) {
        int node = B * 128 + t;
        if (node < NN) {
            row_ptr[node] = beg + s[2 * t] - cnt[2 * t];
            hp[node]      = beg + s[2 * t + 1] - cnt[2 * t + 1];
        }
    }
    for (int p = beg + t; p < end; p += 256) {
        unsigned r = rec[p];
        int idx = (int)((r >> 16) & 127) * 2 + ((r & 0xffffu) >= HALFN ? 1 : 0);
        int loc = atomicAdd(&cur[idx], 1);
        csr[beg + loc] = (ushortT)r;
    }
}

// ---------------- conversions (merged) ----------------
// blocks [0,6250): emb gather+cvt -> CHUNKED bf16 layout [4][NN][64]
// [6250,6762): Wt0; [6762,7274): Wt1

__global__ __launch_bounds__(256)
void k_cvt(const float* __restrict__ emb, const int* __restrict__ gather,
           ushortT* __restrict__ embb,
           const float* __restrict__ Ws0, const float* __restrict__ Wn0,
           ushortT* __restrict__ Wt0,
           const float* __restrict__ Ws1, const float* __restrict__ Wn1,
           ushortT* __restrict__ Wt1) {
    const int b = blockIdx.x;
    if (b < 6250) {
        long long i = ((long long)b * 256 + threadIdx.x) * 8;
        int row = (int)(i >> 8);
        int col = (int)(i & 255);
        long long g = (long long)gather[row] * 256 + col;
        float4 v0 = *(const float4*)(emb + g);
        float4 v1 = *(const float4*)(emb + g + 4);
        uint4 o;
        o.x = bf16rne(v0.x) | (bf16rne(v0.y) << 16);
        o.y = bf16rne(v0.z) | (bf16rne(v0.w) << 16);
        o.z = bf16rne(v1.x) | (bf16rne(v1.y) << 16);
        o.w = bf16rne(v1.z) | (bf16rne(v1.w) << 16);
        // chunked4: [col>>6][row][col&63]
        *(uint4*)(embb + ((long long)(col >> 6) * NN + row) * 64 + (col & 63)) = o;
    } else {
        const bool first = b < 6762;
        const int idx = ((first ? b - 6250 : b - 6762)) * 256 + threadIdx.x;
        const int n = idx >> 9;
        const int k = idx & 511;
        const float* Ws = first ? Ws0 : Ws1;
        const float* Wn = first ? Wn0 : Wn1;
        float v = (k < 256) ? Ws[k * 256 + n] : Wn[(k - 256) * 256 + n];
        (first ? Wt0 : Wt1)[idx] = (ushortT)bf16rne(v);
    }
}

// ---------------- neighbor mean aggregation (R8 single-pass, best measured) ----
// feat [4 chunks][NN][64] bf16, 128B rows = one full line per edge. chunk =
// blockIdx&3 -> XCD pair. Octet owns a node; lane owns 8 dims; 8-edge batches
// with the next batch's indices prefetched while gathers are in flight.

__global__ __launch_bounds__(256)
void k_agg(const ushortT* __restrict__ feat, const int* __restrict__ row_ptr,
           const ushortT* __restrict__ csr, ushortT* __restrict__ out) {
    const int c    = blockIdx.x & 3;
    const int ng   = blockIdx.x >> 2;
    const int node = ng * 32 + (threadIdx.x >> 3);
    const int part = (threadIdx.x & 7) * 8;   // ushort offset within 64-elem row
    if (node >= NN) return;

    const ushortT* fc = feat + (long long)c * CHS4;
    const int beg = row_ptr[node], end = row_ptr[node + 1];

    float s[8] = {0.f, 0.f, 0.f, 0.f, 0.f, 0.f, 0.f, 0.f};

#define ACCUM(q) do { \
        s[0] += __uint_as_float(q.x << 16); \
        s[1] += __uint_as_float(q.x & 0xffff0000u); \
        s[2] += __uint_as_float(q.y << 16); \
        s[3] += __uint_as_float(q.y & 0xffff0000u); \
        s[4] += __uint_as_float(q.z << 16); \
        s[5] += __uint_as_float(q.z & 0xffff0000u); \
        s[6] += __uint_as_float(q.w << 16); \
        s[7] += __uint_as_float(q.w & 0xffff0000u); \
    } while (0)

    int p = beg;

    // head edge: align p to even so uint index loads are 4B-aligned
    if (p < end && (p & 1)) {
        int i0 = (int)__builtin_nontemporal_load(csr + p);
        uintx4 q = *(const uintx4*)(fc + i0 * 64 + part);
        ACCUM(q);
        ++p;
    }

    // preload first batch of 8 indices (4 uints)
    unsigned x0 = 0, x1 = 0, x2 = 0, x3 = 0;
    if (p + 7 < end) {
        const unsigned* cp = (const unsigned*)(csr + p);
        x0 = __builtin_nontemporal_load(cp + 0);
        x1 = __builtin_nontemporal_load(cp + 1);
        x2 = __builtin_nontemporal_load(cp + 2);
        x3 = __builtin_nontemporal_load(cp + 3);
    }

    while (p + 7 < end) {
        uintx4 q0 = *(const uintx4*)(fc + (int)(x0 & 0xffffu) * 64 + part);
        uintx4 q1 = *(const uintx4*)(fc + (int)(x0 >> 16)     * 64 + part);
        uintx4 q2 = *(const uintx4*)(fc + (int)(x1 & 0xffffu) * 64 + part);
        uintx4 q3 = *(const uintx4*)(fc + (int)(x1 >> 16)     * 64 + part);
        uintx4 q4 = *(const uintx4*)(fc + (int)(x2 & 0xffffu) * 64 + part);
        uintx4 q5 = *(const uintx4*)(fc + (int)(x2 >> 16)     * 64 + part);
        uintx4 q6 = *(const uintx4*)(fc + (int)(x3 & 0xffffu) * 64 + part);
        uintx4 q7 = *(const uintx4*)(fc + (int)(x3 >> 16)     * 64 + part);

        const int np = p + 8;
        if (np + 7 < end) {
            const unsigned* cp = (const unsigned*)(csr + np);
            x0 = __builtin_nontemporal_load(cp + 0);
            x1 = __builtin_nontemporal_load(cp + 1);
            x2 = __builtin_nontemporal_load(cp + 2);
            x3 = __builtin_nontemporal_load(cp + 3);
        }

        ACCUM(q0); ACCUM(q1); ACCUM(q2); ACCUM(q3);
        ACCUM(q4); ACCUM(q5); ACCUM(q6); ACCUM(q7);
        p = np;
    }

    for (; p < end; ++p) {
        int i0 = (int)__builtin_nontemporal_load(csr + p);
        uintx4 q = *(const uintx4*)(fc + i0 * 64 + part);
        ACCUM(q);
    }
#undef ACCUM

    float inv = 1.0f / fmaxf((float)(end - beg), 1.0f);
    uintx4 o;
    o.x = bf16rne(s[0] * inv) | (bf16rne(s[1] * inv) << 16);
    o.y = bf16rne(s[2] * inv) | (bf16rne(s[3] * inv) << 16);
    o.z = bf16rne(s[4] * inv) | (bf16rne(s[5] * inv) << 16);
    o.w = bf16rne(s[6] * inv) | (bf16rne(s[7] * inv) << 16);
    __builtin_nontemporal_store(o, (uintx4*)(out + ((long long)c * NN + node) * 64 + part));
}

// ---------------- dual GEMM, 128x256 tile, 512 threads (8 waves, 2M x 4N) -----
// R10: (a) __launch_bounds__(512,4) -> 2 blocks/CU co-residency (was 1);
// (b) C written through LDS (reusing the 24KB staging buffer after the K-loop)
// in row groups, stored fully coalesced: bf16 path 128B row-chunks, f32 path
// float4 rows with sumsq folded into the store loop. Replaces 16 scalar 2B
// scattered stores/thread (25% line efficiency) with 16B coalesced stores.

template<int RELU, int NORM>
__global__ __launch_bounds__(512, 4)
void k_gemm(const ushortT* __restrict__ Aself, const ushortT* __restrict__ Aneigh,
            const ushortT* __restrict__ Wt, const float* __restrict__ bias,
            ushortT* __restrict__ Cb, float* __restrict__ Cf, float* __restrict__ norm_acc) {
    __shared__ ushortT LDSBUF[12288];   // As[4096] | Bs[8192]; reused for C staging
    __shared__ float red[8];
    ushortT* As = LDSBUF;
    ushortT* Bs = LDSBUF + 4096;

    const int t = threadIdx.x;
    const int w = t >> 6;          // wave 0..7
    const int lane = t & 63;
    const int wm = w >> 2;         // 0..1  (M half)
    const int wn = w & 3;          // 0..3  (N quarter)
    const int m0 = blockIdx.x * 128;

    const int ar = t >> 2;        // staging row (0..127)
    const int cu = (t & 3) * 8;   // ushort offset within 32-elem k-row

    const long long gA = (long long)min(m0 + ar, NN - 1) * 64 + cu;

    const unsigned ldsA = w * 512;   // wave-uniform base (ushorts); +lane*16B by HW
    const unsigned ldsB = w * 512;

    const int fm = lane & 15;
    const int fk = (lane >> 4) * 8;

    floatx4 acc[4][4];
#pragma unroll
    for (int i = 0; i < 4; ++i)
#pragma unroll
        for (int j = 0; j < 4; ++j) acc[i][j] = (floatx4){0.f, 0.f, 0.f, 0.f};

    for (int kt = 0; kt < 512; kt += 32) {
        const int kc = (kt < 256) ? kt : kt - 256;
        const ushortT* Ab = ((kt < 256) ? Aself : Aneigh)
                          + (long long)(kc >> 6) * CHS4 + (kc & 32);

        __syncthreads();
        ASYNC16(Ab + gA, As + ldsA);
#pragma unroll
        for (int i = 0; i < 2; ++i)
            ASYNC16(Wt + (i * 128 + ar) * 512 + kt + cu, Bs + i * 4096 + ldsB);
        __syncthreads();

        short8 af[4], bf[4];
#pragma unroll
        for (int i = 0; i < 4; ++i)
            af[i] = *(const short8*)&As[(wm * 64 + i * 16 + fm) * 32 + fk];
#pragma unroll
        for (int j = 0; j < 4; ++j)
            bf[j] = *(const short8*)&Bs[(wn * 64 + j * 16 + fm) * 32 + fk];
#pragma unroll
        for (int i = 0; i < 4; ++i)
#pragma unroll
            for (int j = 0; j < 4; ++j)
                acc[i][j] = __builtin_amdgcn_mfma_f32_16x16x32_bf16(af[i], bf[j], acc[i][j], 0, 0, 0);
    }

    float bj[4];
#pragma unroll
    for (int j = 0; j < 4; ++j) bj[j] = bias[wn * 64 + j * 16 + fm];

    __syncthreads();   // all waves done reading As/Bs before reuse as C stage

    if (!NORM) {
        // ---- bf16 chunked C: 4 groups of 32 rows via LDS, coalesced 16B stores
        ushortT (*Cs)[256] = (ushortT(*)[256])LDSBUF;   // 16KB
#pragma unroll
        for (int g = 0; g < 4; ++g) {
            if (wm == (g >> 1)) {
#pragma unroll
                for (int ii = 0; ii < 2; ++ii) {
                    const int i = (g & 1) * 2 + ii;
#pragma unroll
                    for (int r = 0; r < 4; ++r) {
                        const int lrow = ii * 16 + (lane >> 4) * 4 + r;
#pragma unroll
                        for (int j = 0; j < 4; ++j) {
                            const int col = wn * 64 + j * 16 + fm;
                            float v = acc[i][j][r] + bj[j];
                            if (RELU) v = fmaxf(v, 0.0f);
                            Cs[lrow][col] = (ushortT)bf16rne(v);
                        }
                    }
                }
            }
            __syncthreads();
#pragma unroll
            for (int siter = 0; siter < 2; ++siter) {
                const int id = t + siter * 512;   // id = lr*32 + cc*8 + k8
                const int k8 = id & 7;
                const int cc = (id >> 3) & 3;
                const int lr = id >> 5;
                const int R = m0 + g * 32 + lr;
                if (R < NN) {
                    uintx4 val = *(const uintx4*)&Cs[lr][cc * 64 + k8 * 8];
                    *(uintx4*)(Cb + ((long long)cc * NN + R) * 64 + k8 * 8) = val;
                }
            }
            __syncthreads();
        }
    } else {
        // ---- f32 C: 8 groups of 16 rows via LDS; sumsq folded into store loop
        float (*Csf)[256] = (float(*)[256])LDSBUF;      // 16KB
        float sumsq = 0.0f;
#pragma unroll
        for (int g = 0; g < 8; ++g) {
            if (wm == (g >> 2)) {
                const int i = g & 3;
#pragma unroll
                for (int r = 0; r < 4; ++r) {
                    const int lrow = (lane >> 4) * 4 + r;
#pragma unroll
                    for (int j = 0; j < 4; ++j) {
                        const int col = wn * 64 + j * 16 + fm;
                        Csf[lrow][col] = acc[i][j][r] + bj[j];
                    }
                }
            }
            __syncthreads();
#pragma unroll
            for (int siter = 0; siter < 2; ++siter) {
                const int id = t + siter * 512;   // id = lr*64 + k
                const int lr = id >> 6;
                const int k  = id & 63;
                const int R = m0 + g * 16 + lr;
                if (R < NN) {
                    float4 val = *(const float4*)&Csf[lr][k * 4];
                    sumsq += val.x * val.x + val.y * val.y + val.z * val.z + val.w * val.w;
                    *(float4*)(Cf + (long long)R * 256 + k * 4) = val;
                }
            }
            __syncthreads();
        }
#pragma unroll
        for (int off = 32; off > 0; off >>= 1) sumsq += __shfl_down(sumsq, off);
        if (lane == 0) red[w] = sumsq;
        __syncthreads();
        if (t == 0) {
            float tot = 0.f;
#pragma unroll
            for (int i = 0; i < 8; ++i) tot += red[i];
            atomicAdd(norm_acc, tot);
        }
    }
}

__global__ void k_scale(float* __restrict__ out, const float* __restrict__ nrm) {
    const float s = 1.0f / sqrtf(*nrm);
    long long i = ((long long)blockIdx.x * 256 + threadIdx.x) * 4;
    float4 v = *(float4*)&out[i];
    v.x *= s; v.y *= s; v.z *= s; v.w *= s;
    *(float4*)&out[i] = v;
}

// ---------------- launch ----------------

extern "C" void kernel_launch(void* const* d_in, const int* in_sizes, int n_in,
                              void* d_out, int out_size, void* d_ws, size_t ws_size,
                              hipStream_t stream) {
    const int*   input_nodes = (const int*)d_in[0];
    const int*   esrc = (const int*)d_in[1];
    const int*   edst = (const int*)d_in[2];
    const float* emb  = (const float*)d_in[3];
    const float* Ws0  = (const float*)d_in[4];
    const float* Wn0  = (const float*)d_in[5];
    const float* b0   = (const float*)d_in[6];
    const float* Ws1  = (const float*)d_in[7];
    const float* Wn1  = (const float*)d_in[8];
    const float* b1   = (const float*)d_in[9];
    float* out = (float*)d_out;

    char* base = (char*)d_ws;
    ushortT*  embb    = (ushortT*) (base);                  // 25,600,000
    ushortT*  h1b     = (ushortT*) (base + 25600000);       // 25,600,000
    ushortT*  hnb     = (ushortT*) (base + 51200000);       // 25,600,000
    unsigned* rec     = (unsigned*)(base + 76800000);       //  6,400,000
    ushortT*  csr     = (ushortT*) (base + 83200000);       //  3,200,000
    ushortT*  Wt0     = (ushortT*) (base + 86400000);       //    262,144
    ushortT*  Wt1     = (ushortT*) (base + 86662144);       //    262,144
    int*      row_ptr = (int*)     (base + 86924288);       //    200,016
    int*      hp      = (int*)     (base + 87124304);       //    200,000
    int*      bcnt    = (int*)     (base + 87324304);       //      1,600
    int*      bbase   = (int*)     (base + 87325904);       //      1,600
    int*      cursor  = (int*)     (base + 87327504);       //      1,600
    float*    nrm     = (float*)   (base + 87329104);       //          4

    hipMemsetAsync(bcnt, 0, NBUCK * sizeof(int), stream);
    k_bhist <<<391,   256, 0, stream>>>(edst, bcnt);
    k_bscan <<<1,     512, 0, stream>>>(bcnt, bbase, cursor, row_ptr, nrm);
    k_bin   <<<782,   256, 0, stream>>>(esrc, edst, cursor, rec);
    k_csr   <<<NBUCK, 256, 0, stream>>>(rec, bbase, row_ptr, hp, csr);

    k_cvt<<<7274, 256, 0, stream>>>(emb, input_nodes, embb, Ws0, Wn0, Wt0, Ws1, Wn1, Wt1);

    const int GEMM_BLOCKS = (NN + 127) / 128;     // 391
    const int AGG_BLOCKS  = ((NN + 31) / 32) * 4; // 6252 (node-group-of-32 x chunk)

    // layer 0
    k_agg<<<AGG_BLOCKS, 256, 0, stream>>>(embb, row_ptr, csr, hnb);
    k_gemm<1, 0><<<GEMM_BLOCKS, 512, 0, stream>>>(embb, hnb, Wt0, b0, h1b, nullptr, nullptr);

    // layer 1
    k_agg<<<AGG_BLOCKS, 256, 0, stream>>>(h1b, row_ptr, csr, hnb);
    k_gemm<0, 1><<<GEMM_BLOCKS, 512, 0, stream>>>(h1b, hnb, Wt1, b1, nullptr, out, nrm);

    k_scale<<<NN * DF / 4 / 256, 256, 0, stream>>>(out, nrm);
}